// Round 10
// baseline (205.925 us; speedup 1.0000x reference)
//
#include <hip/hip_runtime.h>
#include <hip/hip_bf16.h>

typedef __attribute__((ext_vector_type(8))) short short8;     // 8 bf16 (MFMA A/B frag, K=32)
typedef __attribute__((ext_vector_type(4))) float float4v;    // MFMA C/D frag
typedef __attribute__((ext_vector_type(4))) _Float16 half4;   // f16 A/B frag, K=16
typedef __attribute__((ext_vector_type(2))) __fp16 fp16x2;    // cvt_pkrtz result type

// ---------------------------------------------------------------------------
// fp32 -> bf16 elementwise convert (vectorized: 4 floats -> 4 bf16 per thread)
// ---------------------------------------------------------------------------
__global__ __launch_bounds__(256) void cvt_f32_bf16(
    const float* __restrict__ in, __hip_bfloat16* __restrict__ out, int n4) {
  const int i = blockIdx.x * 256 + threadIdx.x;
  if (i >= n4) return;
  const float4 v = *(const float4*)(in + (size_t)i * 4);
  __hip_bfloat16 o[4];
  o[0] = __float2bfloat16(v.x); o[1] = __float2bfloat16(v.y);
  o[2] = __float2bfloat16(v.z); o[3] = __float2bfloat16(v.w);
  *(uint2*)(out + (size_t)i * 4) = *(const uint2*)o;
}

// ---------------------------------------------------------------------------
// Transpose + convert: in fp32 (R x C) -> out bf16 (C x R). R,C mult of 32.
// ---------------------------------------------------------------------------
__global__ __launch_bounds__(256) void transpose_f32_bf16(
    const float* __restrict__ in, __hip_bfloat16* __restrict__ out,
    int R, int C) {
  __shared__ __hip_bfloat16 tile[32][33];
  const int c0 = blockIdx.x * 32, r0 = blockIdx.y * 32;
  const int tx = threadIdx.x & 31, ty = threadIdx.x >> 5;  // 256 thr: ty 0..7
  #pragma unroll
  for (int i = ty; i < 32; i += 8)
    tile[i][tx] = __float2bfloat16(in[(size_t)(r0 + i) * C + (c0 + tx)]);
  __syncthreads();
  #pragma unroll
  for (int i = ty; i < 32; i += 8)
    out[(size_t)(c0 + i) * R + (r0 + tx)] = tile[tx][i];
}

// ---------------------------------------------------------------------------
// gemm_bt: C (MxN, OutT) = A (MxK, row-major bf16) @ Bt^T  (Bt is NxK bf16)
// 128x128 tile, BK=64, 256 threads = 4 waves. m97-style global_load_lds
// width=16 staging, stride-64 LDS with XOR chunk swizzle. (r6: 2x+ win; frozen)
// ---------------------------------------------------------------------------
template <typename OutT>
__global__ __launch_bounds__(256) void gemm_bt(
    const __hip_bfloat16* __restrict__ A,
    const __hip_bfloat16* __restrict__ Bt,
    OutT* __restrict__ C,
    int M, int N, int K) {
  __shared__ __hip_bfloat16 lA[128][64];
  __shared__ __hip_bfloat16 lB[128][64];
  const int t = threadIdx.x;
  const int lane = t & 63, wave = t >> 6;
  const int quad = lane >> 4, ln = lane & 15;
  const int m0 = blockIdx.y * 128, n0 = blockIdx.x * 128;
  const int wm = (wave >> 1) * 64, wn = (wave & 1) * 64;
  const int srow = lane >> 3;                    // 0..7
  const int schunk = ((lane & 7) ^ srow) * 8;    // swizzled elem offset

  float4v acc[4][4];
  #pragma unroll
  for (int i = 0; i < 4; ++i)
    #pragma unroll
    for (int j = 0; j < 4; ++j)
      acc[i][j] = (float4v){0.f, 0.f, 0.f, 0.f};

  for (int kt = 0; kt < K; kt += 64) {
    __syncthreads();   // previous iter's frag reads done before DMA overwrite
    #pragma unroll
    for (int q = 0; q < 4; ++q) {
      const int rbase = wave * 32 + q * 8;       // wave-uniform 8-row group
      __builtin_amdgcn_global_load_lds(
          (const __attribute__((address_space(1))) void*)
              (A + (size_t)(m0 + rbase + srow) * K + kt + schunk),
          (__attribute__((address_space(3))) void*)&lA[rbase][0], 16, 0, 0);
      __builtin_amdgcn_global_load_lds(
          (const __attribute__((address_space(1))) void*)
              (Bt + (size_t)(n0 + rbase + srow) * K + kt + schunk),
          (__attribute__((address_space(3))) void*)&lB[rbase][0], 16, 0, 0);
    }
    __syncthreads();   // vmcnt(0) drain: DMA complete, LDS visible
    #pragma unroll
    for (int step = 0; step < 2; ++step) {
      short8 af[4], bf[4];
      #pragma unroll
      for (int i = 0; i < 4; ++i)
        af[i] = *(const short8*)&lA[wm + i * 16 + ln][((step * 4 + quad) ^ (ln & 7)) * 8];
      #pragma unroll
      for (int j = 0; j < 4; ++j)
        bf[j] = *(const short8*)&lB[wn + j * 16 + ln][((step * 4 + quad) ^ (ln & 7)) * 8];
      #pragma unroll
      for (int i = 0; i < 4; ++i)
        #pragma unroll
        for (int j = 0; j < 4; ++j)
          acc[i][j] = __builtin_amdgcn_mfma_f32_16x16x32_bf16(af[i], bf[j], acc[i][j], 0, 0, 0);
    }
  }
  // Epilogue. C/D layout: row = quad*4 + reg, col = lane&15 (m89/m91-verified).
  #pragma unroll
  for (int i = 0; i < 4; ++i)
    #pragma unroll
    for (int j = 0; j < 4; ++j)
      #pragma unroll
      for (int r = 0; r < 4; ++r) {
        const int row = m0 + wm + i * 16 + quad * 4 + r;
        const int col = n0 + wn + j * 16 + ln;
        if constexpr (__is_same(OutT, float))
          C[(size_t)row * N + col] = acc[i][j][r];
        else
          C[(size_t)row * N + col] = __float2bfloat16(acc[i][j][r]);
      }
}

// ---------------------------------------------------------------------------
// RoPE + reshape: qkv (4096 x 3072 bf16) -> Q, K as (b,h,s,d) = (32, 2048, 64)
// Q scaled by (1/sqrt(64)) * log2(e): attention scores live in exp2 domain.
// ---------------------------------------------------------------------------
__global__ __launch_bounds__(512) void rope_reshape(
    const __hip_bfloat16* __restrict__ qkv,
    __hip_bfloat16* __restrict__ Q,
    __hip_bfloat16* __restrict__ K) {
  const int row = blockIdx.x;          // b*2048 + s
  const int s = row & 2047;
  const int b = row >> 11;
  const int t = threadIdx.x;
  const int h = t >> 5, pr = t & 31;
  const int d0 = pr * 2;
  const float freq = powf(10000.f, -(float)d0 / 64.f);
  const float ang = (float)s * freq;
  float sn, cs;
  sincosf(ang, &sn, &cs);
  const float qs = 0.125f * 1.44269504088896340736f;  // (1/8)*log2(e)

  const size_t in_base = (size_t)row * 3072;
  const size_t o = (((size_t)(b * 16 + h)) * 2048 + s) * 64 + d0;

  __hip_bfloat162 q2 = *(const __hip_bfloat162*)&qkv[in_base + h * 64 + d0];
  float x1 = __bfloat162float(q2.x), x2 = __bfloat162float(q2.y);
  __hip_bfloat162 qo;
  qo.x = __float2bfloat16((x1 * cs - x2 * sn) * qs);
  qo.y = __float2bfloat16((x1 * sn + x2 * cs) * qs);
  *(__hip_bfloat162*)&Q[o] = qo;

  __hip_bfloat162 k2 = *(const __hip_bfloat162*)&qkv[in_base + 1024 + h * 64 + d0];
  x1 = __bfloat162float(k2.x); x2 = __bfloat162float(k2.y);
  __hip_bfloat162 ko;
  ko.x = __float2bfloat16(x1 * cs - x2 * sn);
  ko.y = __float2bfloat16(x1 * sn + x2 * cs);
  *(__hip_bfloat162*)&K[o] = ko;
}

// ---------------------------------------------------------------------------
// V transpose + f16 convert: qkv v-part -> Vt (b,h,d,s) f16 = (32, 64, 2048).
// ---------------------------------------------------------------------------
__global__ __launch_bounds__(256) void v_transpose(
    const __hip_bfloat16* __restrict__ qkv,
    _Float16* __restrict__ Vt) {
  __shared__ _Float16 tile[64][65];
  const int bh = blockIdx.y;
  const int h = bh & 15, b = bh >> 4;
  const int s0 = blockIdx.x * 64;
  const int tx = threadIdx.x & 63, ty = threadIdx.x >> 6;  // ty 0..3
  #pragma unroll
  for (int i = ty; i < 64; i += 4)
    tile[i][tx] = (_Float16)__bfloat162float(
        qkv[(size_t)(b * 2048 + s0 + i) * 3072 + 2048 + h * 64 + tx]);
  __syncthreads();
  #pragma unroll
  for (int i = ty; i < 64; i += 4)
    Vt[((size_t)bh * 64 + i) * 2048 + s0 + tx] = tile[tx][i];
}

// ---------------------------------------------------------------------------
// Flash-style causal attention, WAVE-SPLIT-SK edition.
// r9's profile showed the block is LDS-BANDWIDTH bound: all 4 waves read the
// full 64x64 K/V tile (4x redundancy, ~72 KB LDS reads per block-iter).
// Now wave w owns sk-quarter [w*16, w*16+16) x ALL 64 q:
//   - lK reads per wave-iter: 2 b128 (16 sk x 64 d); lV: 4 b64 -> ~16 KB/block-iter
//   - Q for all 64 q held in registers (loaded once per phase)
//   - S^T = K.Q^T (16x16x32 bf16, A=K m=sk, B=Q n=q) -> C-frags
//   - P^T = exp2(S^T) feeds PV directly as B-operand of 16x16x16f16
//     (C-layout == K=16 B-layout, r9-HW-verified); A = V^T b64 frags
//   - per-wave partial O^T[64d][64q] (64 VGPRs) + partial l[64q]
//   - end-of-phase cross-wave reduction via LDS (reuses lK/lV space,
//     2 rounds x 24 KB, wave 0 sums + stores)
// Staging/dbuf/pairing/XCD swizzle unchanged from r7/r9.
// ---------------------------------------------------------------------------
__global__ __launch_bounds__(256) void attention(
    const __hip_bfloat16* __restrict__ Q,
    const __hip_bfloat16* __restrict__ K,
    const _Float16* __restrict__ Vt,
    __hip_bfloat16* __restrict__ attn) {
  __shared__ __align__(16) char smem[32768];
  __hip_bfloat16 (*lK)[64][64] = (__hip_bfloat16(*)[64][64])smem;          // [2][64][64]
  _Float16       (*lV)[64][64] = (_Float16(*)[64][64])(smem + 16384);      // [2][64][64]
  float* red = (float*)smem;                 // 24 KB reduce region (aliases lK/lV)
  __shared__ float lbuf[3][4][16];           // l partials of waves 1..3

  const int t = threadIdx.x;
  const int lane = t & 63, w = t >> 6;
  const int quad = lane >> 4, ln = lane & 15;
  const int bh = blockIdx.x;                  // id%8 = bh%8 -> XCD locality
  const int pair = blockIdx.y;
  const size_t base = (size_t)bh * 2048 * 64;
  const __hip_bfloat16* Qb = Q + base;
  const __hip_bfloat16* Kb = K + base;
  const _Float16* Vb = Vt + base;
  const int b = bh >> 4, h = bh & 15;

  half4 vones;
  #pragma unroll
  for (int i = 0; i < 4; ++i) vones[i] = (_Float16)1.0f;

  const int srow = lane >> 3;                    // 0..7
  const int schunk = ((lane & 7) ^ srow) * 8;    // swizzled elem offset
  const int rb0 = w * 16;                        // this wave's staging rows

  #pragma unroll
  for (int ph = 0; ph < 2; ++ph) {
    const int qtile = (ph == 0) ? pair : 31 - pair;
    const int q0 = qtile * 64;

    __syncthreads();   // previous phase fully done (incl. wave0 reduce reads)

    // stage kt=0 into buf 0 (each wave: 2 K-row-groups + 2 V-row-groups)
    #pragma unroll
    for (int g = 0; g < 2; ++g) {
      const int rbase = rb0 + g * 8;
      __builtin_amdgcn_global_load_lds(
          (const __attribute__((address_space(1))) void*)
              (Kb + (size_t)(rbase + srow) * 64 + schunk),
          (__attribute__((address_space(3))) void*)&lK[0][rbase][0], 16, 0, 0);
      __builtin_amdgcn_global_load_lds(
          (const __attribute__((address_space(1))) void*)
              (Vb + (size_t)(rbase + srow) * 2048 + schunk),
          (__attribute__((address_space(3))) void*)&lV[0][rbase][0], 16, 0, 0);
    }

    // Q fragments for ALL 64 q-rows (B-operand K=32: n=ln, k=quad*8+j)
    short8 qf[4][2];
    #pragma unroll
    for (int j = 0; j < 4; ++j) {
      const size_t qrow = (size_t)(q0 + j * 16 + ln) * 64;
      qf[j][0] = *(const short8*)(Qb + qrow + quad * 8);
      qf[j][1] = *(const short8*)(Qb + qrow + 32 + quad * 8);
    }

    float4v acc_o[4][4];   // O^T partial: [dt][qt], d=dt*16+quad*4+r, q=qt*16+ln
    #pragma unroll
    for (int dt = 0; dt < 4; ++dt)
      #pragma unroll
      for (int j = 0; j < 4; ++j)
        acc_o[dt][j] = (float4v){0.f, 0.f, 0.f, 0.f};
    float4v acc_l[4];      // l partial per q-subtile (rows all equal)
    #pragma unroll
    for (int j = 0; j < 4; ++j) acc_l[j] = (float4v){0.f, 0.f, 0.f, 0.f};

    for (int kt = 0; kt <= qtile; ++kt) {
      const int buf = kt & 1;
      __syncthreads();   // drains DMA(kt); frees buf^1

      if (kt < qtile) {  // prefetch kt+1 into the other buffer — after barrier
        #pragma unroll
        for (int g = 0; g < 2; ++g) {
          const int rbase = rb0 + g * 8;
          __builtin_amdgcn_global_load_lds(
              (const __attribute__((address_space(1))) void*)
                  (Kb + (size_t)((kt + 1) * 64 + rbase + srow) * 64 + schunk),
              (__attribute__((address_space(3))) void*)&lK[buf ^ 1][rbase][0], 16, 0, 0);
          __builtin_amdgcn_global_load_lds(
              (const __attribute__((address_space(1))) void*)
                  (Vb + (size_t)(rbase + srow) * 2048 + (kt + 1) * 64 + schunk),
              (__attribute__((address_space(3))) void*)&lV[buf ^ 1][rbase][0], 16, 0, 0);
        }
      }

      // S^T tile for wave's 16 sk x 64 q: A = K-frag (m = sk = w*16+ln)
      short8 kf[2];
      #pragma unroll
      for (int step = 0; step < 2; ++step)
        kf[step] = *(const short8*)&lK[buf][w * 16 + ln][((step * 4 + quad) ^ (ln & 7)) * 8];
      float4v s4[4];
      #pragma unroll
      for (int j = 0; j < 4; ++j) {
        float4v a = (float4v){0.f, 0.f, 0.f, 0.f};
        a = __builtin_amdgcn_mfma_f32_16x16x32_bf16(kf[0], qf[j][0], a, 0, 0, 0);
        a = __builtin_amdgcn_mfma_f32_16x16x32_bf16(kf[1], qf[j][1], a, 0, 0, 0);
        s4[j] = a;
      }
      if (kt == qtile) {  // diagonal tile: causal mask (exp2(-64) -> 0 in f16)
        #pragma unroll
        for (int j = 0; j < 4; ++j)
          #pragma unroll
          for (int r = 0; r < 4; ++r) {
            const int sk = kt * 64 + w * 16 + quad * 4 + r;
            const int qr = q0 + j * 16 + ln;
            if (sk > qr) s4[j][r] = -64.f;
          }
      }
      // P^T = exp2(S^T) -> f16 B-frags, no LDS round-trip
      half4 pf[4];
      #pragma unroll
      for (int j = 0; j < 4; ++j) {
        const fp16x2 lo = __builtin_amdgcn_cvt_pkrtz(exp2f(s4[j][0]), exp2f(s4[j][1]));
        const fp16x2 hi = __builtin_amdgcn_cvt_pkrtz(exp2f(s4[j][2]), exp2f(s4[j][3]));
        pf[j][0] = (_Float16)lo[0]; pf[j][1] = (_Float16)lo[1];
        pf[j][2] = (_Float16)hi[0]; pf[j][3] = (_Float16)hi[1];
      }
      // l += 1.P^T ; O^T += V^T.P^T  (K=16 f16; A = V^T b64 frags)
      #pragma unroll
      for (int j = 0; j < 4; ++j)
        acc_l[j] = __builtin_amdgcn_mfma_f32_16x16x16f16(vones, pf[j], acc_l[j], 0, 0, 0);
      #pragma unroll
      for (int dt = 0; dt < 4; ++dt) {
        half4 vf = *(const half4*)&lV[buf][dt * 16 + ln]
            [(((w * 2 + (quad >> 1)) ^ (ln & 7)) * 8) + (quad & 1) * 4];
        #pragma unroll
        for (int j = 0; j < 4; ++j)
          acc_o[dt][j] = __builtin_amdgcn_mfma_f32_16x16x16f16(vf, pf[j], acc_o[dt][j], 0, 0, 0);
      }
    }

    // ---- cross-wave reduction: O = sum_w O_w, l = sum_w l_w; wave0 stores ----
    __syncthreads();   // all compute done; lK/lV space free -> reduce buffer
    float inv_l[4];
    #pragma unroll
    for (int rnd = 0; rnd < 2; ++rnd) {
      if (w > 0) {     // write partials for d-half rnd (dt = rnd*2, rnd*2+1)
        #pragma unroll
        for (int dL = 0; dL < 2; ++dL)
          #pragma unroll
          for (int j = 0; j < 4; ++j)
            *(float4v*)&red[(w - 1) * 2048 + (dL * 4 + j) * 256 + lane * 4] =
                acc_o[rnd * 2 + dL][j];
        if (rnd == 0 && quad == 0) {
          #pragma unroll
          for (int j = 0; j < 4; ++j) lbuf[w - 1][j][ln] = acc_l[j][0];
        }
      }
      __syncthreads();
      if (w == 0) {
        if (rnd == 0) {
          #pragma unroll
          for (int j = 0; j < 4; ++j) {
            const float lt = acc_l[j][0] + lbuf[0][j][ln] + lbuf[1][j][ln] + lbuf[2][j][ln];
            inv_l[j] = 1.0f / lt;
          }
        }
        #pragma unroll
        for (int dL = 0; dL < 2; ++dL)
          #pragma unroll
          for (int j = 0; j < 4; ++j) {
            float4v s = acc_o[rnd * 2 + dL][j];
            #pragma unroll
            for (int src = 0; src < 3; ++src)
              s += *(const float4v*)&red[src * 2048 + (dL * 4 + j) * 256 + lane * 4];
            const int dt = rnd * 2 + dL;
            const int qr = q0 + j * 16 + ln;
            __hip_bfloat16 o4[4];
            #pragma unroll
            for (int r = 0; r < 4; ++r)
              o4[r] = __float2bfloat16(s[r] * inv_l[j]);
            *(uint2*)&attn[(size_t)(b * 2048 + qr) * 1024 + h * 64 + dt * 16 + quad * 4] =
                *(const uint2*)o4;
          }
      }
      __syncthreads();   // wave0 done reading before next round's writes
    }
  }
}

// ---------------------------------------------------------------------------
extern "C" void kernel_launch(void* const* d_in, const int* in_sizes, int n_in,
                              void* d_out, int out_size, void* d_ws, size_t ws_size,
                              hipStream_t stream) {
  const float* x    = (const float*)d_in[0];  // (2,2048,1024) fp32
  const float* Wqkv = (const float*)d_in[1];  // (1024,3072)   fp32
  const float* Wout = (const float*)d_in[2];  // (1024,1024)   fp32
  float* out = (float*)d_out;                 // (2,2048,1024) fp32

  __hip_bfloat16* ws = (__hip_bfloat16*)d_ws;
  __hip_bfloat16* xb    = ws;                          // 4096*1024
  __hip_bfloat16* WqkvT = xb    + (size_t)4096 * 1024; // 3072*1024
  __hip_bfloat16* WoutT = WqkvT + (size_t)3072 * 1024; // 1024*1024
  __hip_bfloat16* qkv   = WoutT + (size_t)1024 * 1024; // 4096*3072
  __hip_bfloat16* Q     = qkv   + (size_t)4096 * 3072; // 32*2048*64
  __hip_bfloat16* K     = Q     + (size_t)32 * 2048 * 64;
  _Float16*       Vt    = (_Float16*)(K + (size_t)32 * 2048 * 64);
  __hip_bfloat16* attn  = (__hip_bfloat16*)(Vt + (size_t)32 * 2048 * 64);

  cvt_f32_bf16<<<4096, 256, 0, stream>>>(x, xb, 4096 * 1024 / 4);
  transpose_f32_bf16<<<dim3(3072 / 32, 1024 / 32), 256, 0, stream>>>(Wqkv, WqkvT, 1024, 3072);
  transpose_f32_bf16<<<dim3(1024 / 32, 1024 / 32), 256, 0, stream>>>(Wout, WoutT, 1024, 1024);
  gemm_bt<__hip_bfloat16><<<dim3(3072 / 128, 4096 / 128), 256, 0, stream>>>(xb, WqkvT, qkv, 4096, 3072, 1024);
  rope_reshape<<<4096, 512, 0, stream>>>(qkv, Q, K);
  v_transpose<<<dim3(32, 32), 256, 0, stream>>>(qkv, Vt);
  attention<<<dim3(32, 16), 256, 0, stream>>>(Q, K, Vt, attn);
  gemm_bt<float><<<dim3(1024 / 128, 4096 / 128), 256, 0, stream>>>(attn, WoutT, out, 4096, 1024, 1024);
}

// Round 11
// 191.114 us; speedup vs baseline: 1.0775x; 1.0775x over previous
//
#include <hip/hip_runtime.h>
#include <hip/hip_bf16.h>

typedef __attribute__((ext_vector_type(8))) short short8;     // 8 bf16 (MFMA A/B frag, K=32)
typedef __attribute__((ext_vector_type(4))) float float4v;    // MFMA C/D frag

// ---------------------------------------------------------------------------
// fp32 -> bf16 elementwise convert (vectorized: 4 floats -> 4 bf16 per thread)
// ---------------------------------------------------------------------------
__global__ __launch_bounds__(256) void cvt_f32_bf16(
    const float* __restrict__ in, __hip_bfloat16* __restrict__ out, int n4) {
  const int i = blockIdx.x * 256 + threadIdx.x;
  if (i >= n4) return;
  const float4 v = *(const float4*)(in + (size_t)i * 4);
  __hip_bfloat16 o[4];
  o[0] = __float2bfloat16(v.x); o[1] = __float2bfloat16(v.y);
  o[2] = __float2bfloat16(v.z); o[3] = __float2bfloat16(v.w);
  *(uint2*)(out + (size_t)i * 4) = *(const uint2*)o;
}

// ---------------------------------------------------------------------------
// Transpose + convert: in fp32 (R x C) -> out bf16 (C x R). R,C mult of 32.
// ---------------------------------------------------------------------------
__global__ __launch_bounds__(256) void transpose_f32_bf16(
    const float* __restrict__ in, __hip_bfloat16* __restrict__ out,
    int R, int C) {
  __shared__ __hip_bfloat16 tile[32][33];
  const int c0 = blockIdx.x * 32, r0 = blockIdx.y * 32;
  const int tx = threadIdx.x & 31, ty = threadIdx.x >> 5;  // 256 thr: ty 0..7
  #pragma unroll
  for (int i = ty; i < 32; i += 8)
    tile[i][tx] = __float2bfloat16(in[(size_t)(r0 + i) * C + (c0 + tx)]);
  __syncthreads();
  #pragma unroll
  for (int i = ty; i < 32; i += 8)
    out[(size_t)(c0 + i) * R + (r0 + tx)] = tile[tx][i];
}

// ---------------------------------------------------------------------------
// gemm_bt: C (MxN, OutT) = A (MxK, row-major bf16) @ Bt^T  (Bt is NxK bf16)
// 128xBN tile (BN = 128 or 64), BK=64, 256 threads = 4 waves.
// m97-style global_load_lds width=16 staging, stride-64 LDS + XOR chunk
// swizzle (r6-verified). BN=64 doubles the grid for small-N GEMMs whose
// 256-block grid left 1 block/CU (barrier stalls fully exposed).
// ---------------------------------------------------------------------------
template <typename OutT, int BN>
__global__ __launch_bounds__(256) void gemm_bt(
    const __hip_bfloat16* __restrict__ A,
    const __hip_bfloat16* __restrict__ Bt,
    OutT* __restrict__ C,
    int M, int N, int K) {
  __shared__ __hip_bfloat16 lA[128][64];
  __shared__ __hip_bfloat16 lB[BN][64];
  constexpr int NJ = BN / 32;                    // j-tiles of 16 per wave
  const int t = threadIdx.x;
  const int lane = t & 63, wave = t >> 6;
  const int quad = lane >> 4, ln = lane & 15;
  const int m0 = blockIdx.y * 128, n0 = blockIdx.x * BN;
  const int wm = (wave >> 1) * 64, wn = (wave & 1) * (BN / 2);
  const int srow = lane >> 3;                    // 0..7
  const int schunk = ((lane & 7) ^ srow) * 8;    // swizzled elem offset

  float4v acc[4][NJ];
  #pragma unroll
  for (int i = 0; i < 4; ++i)
    #pragma unroll
    for (int j = 0; j < NJ; ++j)
      acc[i][j] = (float4v){0.f, 0.f, 0.f, 0.f};

  for (int kt = 0; kt < K; kt += 64) {
    __syncthreads();   // previous iter's frag reads done before DMA overwrite
    #pragma unroll
    for (int q = 0; q < 4; ++q) {
      const int rbase = wave * 32 + q * 8;       // A: 128 rows, 4 groups/wave
      __builtin_amdgcn_global_load_lds(
          (const __attribute__((address_space(1))) void*)
              (A + (size_t)(m0 + rbase + srow) * K + kt + schunk),
          (__attribute__((address_space(3))) void*)&lA[rbase][0], 16, 0, 0);
    }
    #pragma unroll
    for (int g = 0; g < BN / 32; ++g) {
      const int rbase = wave * (BN / 4) + g * 8; // B: BN rows, BN/32 groups/wave
      __builtin_amdgcn_global_load_lds(
          (const __attribute__((address_space(1))) void*)
              (Bt + (size_t)(n0 + rbase + srow) * K + kt + schunk),
          (__attribute__((address_space(3))) void*)&lB[rbase][0], 16, 0, 0);
    }
    __syncthreads();   // vmcnt(0) drain: DMA complete, LDS visible
    #pragma unroll
    for (int step = 0; step < 2; ++step) {
      short8 af[4], bf[NJ];
      #pragma unroll
      for (int i = 0; i < 4; ++i)
        af[i] = *(const short8*)&lA[wm + i * 16 + ln][((step * 4 + quad) ^ (ln & 7)) * 8];
      #pragma unroll
      for (int j = 0; j < NJ; ++j)
        bf[j] = *(const short8*)&lB[wn + j * 16 + ln][((step * 4 + quad) ^ (ln & 7)) * 8];
      #pragma unroll
      for (int i = 0; i < 4; ++i)
        #pragma unroll
        for (int j = 0; j < NJ; ++j)
          acc[i][j] = __builtin_amdgcn_mfma_f32_16x16x32_bf16(af[i], bf[j], acc[i][j], 0, 0, 0);
    }
  }
  // Epilogue. C/D layout: row = quad*4 + reg, col = lane&15 (m89/m91-verified).
  #pragma unroll
  for (int i = 0; i < 4; ++i)
    #pragma unroll
    for (int j = 0; j < NJ; ++j)
      #pragma unroll
      for (int r = 0; r < 4; ++r) {
        const int row = m0 + wm + i * 16 + quad * 4 + r;
        const int col = n0 + wn + j * 16 + ln;
        if constexpr (__is_same(OutT, float))
          C[(size_t)row * N + col] = acc[i][j][r];
        else
          C[(size_t)row * N + col] = __float2bfloat16(acc[i][j][r]);
      }
}

// ---------------------------------------------------------------------------
// Fused QKV prep: rope(Q,K) reshape + V transpose in ONE kernel / one qkv pass.
// Block = (s-tile of 64) x (b*h). Q scaled by (1/8)*log2(e): attention scores
// live in the exp2 domain (single v_exp_f32 per element there).
// ---------------------------------------------------------------------------
__global__ __launch_bounds__(256) void qkv_prep(
    const __hip_bfloat16* __restrict__ qkv,
    __hip_bfloat16* __restrict__ Q,
    __hip_bfloat16* __restrict__ K,
    __hip_bfloat16* __restrict__ Vt) {
  __shared__ __hip_bfloat16 tile[64][65];
  const int s0 = blockIdx.x * 64;
  const int bh = blockIdx.y;
  const int h = bh & 15, b = bh >> 4;
  const int t = threadIdx.x;

  // --- RoPE for Q,K: t = (s_local 0..7) x (pair 0..31), 8 passes over s ---
  const int pr = t & 31, sl = t >> 5;
  const int d0 = pr * 2;
  const float freq = powf(10000.f, -(float)d0 / 64.f);
  const float qs = 0.125f * 1.44269504088896340736f;  // (1/8)*log2(e)
  #pragma unroll
  for (int ss = sl; ss < 64; ss += 8) {
    const int s = s0 + ss;
    float sn, cs;
    sincosf((float)s * freq, &sn, &cs);
    const size_t in_base = (size_t)(b * 2048 + s) * 3072;
    const size_t o = ((size_t)bh * 2048 + s) * 64 + d0;

    __hip_bfloat162 q2 = *(const __hip_bfloat162*)&qkv[in_base + h * 64 + d0];
    float x1 = __bfloat162float(q2.x), x2 = __bfloat162float(q2.y);
    __hip_bfloat162 qo;
    qo.x = __float2bfloat16((x1 * cs - x2 * sn) * qs);
    qo.y = __float2bfloat16((x1 * sn + x2 * cs) * qs);
    *(__hip_bfloat162*)&Q[o] = qo;

    __hip_bfloat162 k2 = *(const __hip_bfloat162*)&qkv[in_base + 1024 + h * 64 + d0];
    x1 = __bfloat162float(k2.x); x2 = __bfloat162float(k2.y);
    __hip_bfloat162 ko;
    ko.x = __float2bfloat16(x1 * cs - x2 * sn);
    ko.y = __float2bfloat16(x1 * sn + x2 * cs);
    *(__hip_bfloat162*)&K[o] = ko;
  }

  // --- V transpose: (s,d) -> Vt[bh][d][s] ---
  const int tx = t & 63, ty = t >> 6;  // ty 0..3
  #pragma unroll
  for (int i = ty; i < 64; i += 4)
    tile[i][tx] = qkv[(size_t)(b * 2048 + s0 + i) * 3072 + 2048 + h * 64 + tx];
  __syncthreads();
  #pragma unroll
  for (int i = ty; i < 64; i += 4)
    Vt[((size_t)bh * 64 + i) * 2048 + s0 + tx] = tile[tx][i];
}

// ---------------------------------------------------------------------------
// Flash-style causal attention — r7 inner loop (the 45 µs optimum: lP round
// trip, q-quarter per wave, dbuf global_load_lds, one barrier/iter), with the
// grid UN-PAIRED: 1024 single-qt blocks, longest-first.
//   LDS 41984 B -> 3 blocks/CU resident; 1024 > 768 so freed slots BACKFILL
//   (r4's decay had grid <= capacity: no queue). qt = 31 - id/32 puts the
//   32-iteration blocks first; bh = id&31 keeps the XCD spread.
// r9/r10 falsified the DS-count and LDS-BW theories (both regressed); the
// residual stall is TLP-starvation, which resident-depth 3 + backfill attacks.
// ---------------------------------------------------------------------------
__global__ __launch_bounds__(256) void attention(
    const __hip_bfloat16* __restrict__ Q,
    const __hip_bfloat16* __restrict__ K,
    const __hip_bfloat16* __restrict__ Vt,
    __hip_bfloat16* __restrict__ attn) {
  __shared__ __hip_bfloat16 lK[2][64][64];    // [buf][sk][d]   XOR-swizzled
  __shared__ __hip_bfloat16 lV[2][64][64];    // [buf][d][sk]   XOR-swizzled
  __shared__ __hip_bfloat16 lP[4][16][72];    // per-wave [q][sk]
  const int t = threadIdx.x;
  const int lane = t & 63, w = t >> 6;
  const int quad = lane >> 4, ln = lane & 15;
  const int id = blockIdx.x;
  const int bh = id & 31;                     // fast index -> XCD spread
  const int qt = 31 - (id >> 5);              // longest q-tiles first
  const int q0 = qt * 64;
  const size_t base = (size_t)bh * 2048 * 64;
  const __hip_bfloat16* Qb = Q + base;
  const __hip_bfloat16* Kb = K + base;
  const __hip_bfloat16* Vb = Vt + base;
  const int b = bh >> 4, h = bh & 15;

  short8 ones;
  #pragma unroll
  for (int i = 0; i < 8; ++i) ones[i] = (short)0x3F80;   // bf16 1.0

  const int srow = lane >> 3;                    // 0..7
  const int schunk = ((lane & 7) ^ srow) * 8;    // swizzled elem offset
  const int rb0 = w * 16;                        // this wave's staging rows

  // stage kt=0 into buf 0 (each wave: 2 K-row-groups + 2 V-row-groups)
  #pragma unroll
  for (int g = 0; g < 2; ++g) {
    const int rbase = rb0 + g * 8;
    __builtin_amdgcn_global_load_lds(
        (const __attribute__((address_space(1))) void*)
            (Kb + (size_t)(rbase + srow) * 64 + schunk),
        (__attribute__((address_space(3))) void*)&lK[0][rbase][0], 16, 0, 0);
    __builtin_amdgcn_global_load_lds(
        (const __attribute__((address_space(1))) void*)
            (Vb + (size_t)(rbase + srow) * 2048 + schunk),
        (__attribute__((address_space(3))) void*)&lV[0][rbase][0], 16, 0, 0);
  }

  // Q fragment (A-operand): m = ln, k = step*32 + quad*8 + j
  short8 qf[2];
  {
    const size_t qrow = (size_t)(q0 + w * 16 + ln) * 64;
    qf[0] = *(const short8*)(Qb + qrow + quad * 8);
    qf[1] = *(const short8*)(Qb + qrow + 32 + quad * 8);
  }

  float4v acc_o[4];
  #pragma unroll
  for (int dt = 0; dt < 4; ++dt) acc_o[dt] = (float4v){0.f, 0.f, 0.f, 0.f};
  float4v acc_l = (float4v){0.f, 0.f, 0.f, 0.f};

  for (int kt = 0; kt <= qt; ++kt) {
    const int buf = kt & 1;
    __syncthreads();   // drains DMA(kt); frees buf^1

    if (kt < qt) {     // prefetch kt+1 into the other buffer — after barrier
      #pragma unroll
      for (int g = 0; g < 2; ++g) {
        const int rbase = rb0 + g * 8;
        __builtin_amdgcn_global_load_lds(
            (const __attribute__((address_space(1))) void*)
                (Kb + (size_t)((kt + 1) * 64 + rbase + srow) * 64 + schunk),
            (__attribute__((address_space(3))) void*)&lK[buf ^ 1][rbase][0], 16, 0, 0);
        __builtin_amdgcn_global_load_lds(
            (const __attribute__((address_space(1))) void*)
                (Vb + (size_t)(rbase + srow) * 2048 + (kt + 1) * 64 + schunk),
            (__attribute__((address_space(3))) void*)&lV[buf ^ 1][rbase][0], 16, 0, 0);
      }
    }

    // S = Q K^T (exp2 domain; Q pre-scaled); B-operand n = sk = ln
    float4v s4[4];
    #pragma unroll
    for (int nt = 0; nt < 4; ++nt) {
      float4v a = (float4v){0.f, 0.f, 0.f, 0.f};
      #pragma unroll
      for (int step = 0; step < 2; ++step) {
        short8 kf = *(const short8*)&lK[buf][nt * 16 + ln][((step * 4 + quad) ^ (ln & 7)) * 8];
        a = __builtin_amdgcn_mfma_f32_16x16x32_bf16(qf[step], kf, a, 0, 0, 0);
      }
      s4[nt] = a;
    }
    if (kt == qt) {  // diagonal tile: causal mask (exp2(-64) ~ 5e-20 -> 0)
      #pragma unroll
      for (int nt = 0; nt < 4; ++nt)
        #pragma unroll
        for (int r = 0; r < 4; ++r) {
          const int sk = kt * 64 + nt * 16 + ln;
          const int qr = q0 + w * 16 + quad * 4 + r;
          if (sk > qr) s4[nt][r] = -64.f;
        }
    }
    // P = exp2(S), straight to LDS in C-layout (wave-private, no barrier)
    #pragma unroll
    for (int nt = 0; nt < 4; ++nt)
      #pragma unroll
      for (int r = 0; r < 4; ++r)
        lP[w][quad * 4 + r][nt * 16 + ln] = __float2bfloat16(exp2f(s4[nt][r]));
    // O += P V ; l += P 1
    #pragma unroll
    for (int step = 0; step < 2; ++step) {
      short8 pf = *(const short8*)&lP[w][ln][step * 32 + quad * 8];
      acc_l = __builtin_amdgcn_mfma_f32_16x16x32_bf16(pf, ones, acc_l, 0, 0, 0);
      #pragma unroll
      for (int dt = 0; dt < 4; ++dt) {
        short8 vf = *(const short8*)&lV[buf][dt * 16 + ln][((step * 4 + quad) ^ (ln & 7)) * 8];
        acc_o[dt] = __builtin_amdgcn_mfma_f32_16x16x32_bf16(pf, vf, acc_o[dt], 0, 0, 0);
      }
    }
  }

  // write O / l  to attn in (b, s, h*64+d) layout
  float inv_l[4];
  #pragma unroll
  for (int r = 0; r < 4; ++r) inv_l[r] = 1.0f / acc_l[r];
  #pragma unroll
  for (int dt = 0; dt < 4; ++dt)
    #pragma unroll
    for (int r = 0; r < 4; ++r) {
      const int qr = q0 + w * 16 + quad * 4 + r;
      const size_t rg = (size_t)(b * 2048 + qr);
      const int col = h * 64 + dt * 16 + ln;
      attn[rg * 1024 + col] = __float2bfloat16(acc_o[dt][r] * inv_l[r]);
    }
}

// ---------------------------------------------------------------------------
extern "C" void kernel_launch(void* const* d_in, const int* in_sizes, int n_in,
                              void* d_out, int out_size, void* d_ws, size_t ws_size,
                              hipStream_t stream) {
  const float* x    = (const float*)d_in[0];  // (2,2048,1024) fp32
  const float* Wqkv = (const float*)d_in[1];  // (1024,3072)   fp32
  const float* Wout = (const float*)d_in[2];  // (1024,1024)   fp32
  float* out = (float*)d_out;                 // (2,2048,1024) fp32

  __hip_bfloat16* ws = (__hip_bfloat16*)d_ws;
  __hip_bfloat16* xb    = ws;                          // 4096*1024
  __hip_bfloat16* WqkvT = xb    + (size_t)4096 * 1024; // 3072*1024
  __hip_bfloat16* WoutT = WqkvT + (size_t)3072 * 1024; // 1024*1024
  __hip_bfloat16* qkv   = WoutT + (size_t)1024 * 1024; // 4096*3072
  __hip_bfloat16* Q     = qkv   + (size_t)4096 * 3072; // 32*2048*64
  __hip_bfloat16* K     = Q     + (size_t)32 * 2048 * 64;
  __hip_bfloat16* Vt    = K     + (size_t)32 * 2048 * 64;
  __hip_bfloat16* attn  = Vt    + (size_t)32 * 2048 * 64;  // dedicated

  cvt_f32_bf16<<<4096, 256, 0, stream>>>(x, xb, 4096 * 1024 / 4);
  transpose_f32_bf16<<<dim3(3072 / 32, 1024 / 32), 256, 0, stream>>>(Wqkv, WqkvT, 1024, 3072);
  transpose_f32_bf16<<<dim3(1024 / 32, 1024 / 32), 256, 0, stream>>>(Wout, WoutT, 1024, 1024);
  gemm_bt<__hip_bfloat16, 128><<<dim3(3072 / 128, 4096 / 128), 256, 0, stream>>>(xb, WqkvT, qkv, 4096, 3072, 1024);
  qkv_prep<<<dim3(32, 32), 256, 0, stream>>>(qkv, Q, K, Vt);
  attention<<<1024, 256, 0, stream>>>(Q, K, Vt, attn);
  gemm_bt<float, 64><<<dim3(1024 / 64, 4096 / 128), 256, 0, stream>>>(attn, WoutT, out, 4096, 1024, 1024);
}

// Round 12
// 183.261 us; speedup vs baseline: 1.1237x; 1.0428x over previous
//
#include <hip/hip_runtime.h>
#include <hip/hip_bf16.h>

typedef __attribute__((ext_vector_type(8))) short short8;     // 8 bf16 (MFMA A/B frag, K=32)
typedef __attribute__((ext_vector_type(4))) float float4v;    // MFMA C/D frag

// ---------------------------------------------------------------------------
// fp32 -> bf16 elementwise convert (vectorized: 4 floats -> 4 bf16 per thread)
// ---------------------------------------------------------------------------
__global__ __launch_bounds__(256) void cvt_f32_bf16(
    const float* __restrict__ in, __hip_bfloat16* __restrict__ out, int n4) {
  const int i = blockIdx.x * 256 + threadIdx.x;
  if (i >= n4) return;
  const float4 v = *(const float4*)(in + (size_t)i * 4);
  __hip_bfloat16 o[4];
  o[0] = __float2bfloat16(v.x); o[1] = __float2bfloat16(v.y);
  o[2] = __float2bfloat16(v.z); o[3] = __float2bfloat16(v.w);
  *(uint2*)(out + (size_t)i * 4) = *(const uint2*)o;
}

// ---------------------------------------------------------------------------
// RoPE table: tab[s][p] = (cos, sin)(s * 10000^(-2p/64)) for s<2048, p<32.
// 65536 entries, 512 KB — computed once, L2-resident for qkv_prep. Removes
// 2M sincosf + 1M powf from qkv_prep (each of its 1024 blocks recomputed the
// same angles).
// ---------------------------------------------------------------------------
__global__ __launch_bounds__(256) void rope_table(float2* __restrict__ tab) {
  const int i = blockIdx.x * 256 + threadIdx.x;   // 65536
  const int s = i >> 5, p = i & 31;
  const float freq = powf(10000.f, -(float)(p * 2) / 64.f);
  float sn, cs;
  sincosf((float)s * freq, &sn, &cs);
  tab[i] = make_float2(cs, sn);
}

// ---------------------------------------------------------------------------
// Fused weight transposes: z=0 -> WqkvT (1024x3072 -> 3072x1024),
// z=1 -> WoutT (1024x1024 -> 1024x1024). fp32 in, bf16 out.
// ---------------------------------------------------------------------------
__global__ __launch_bounds__(256) void prep_weights(
    const float* __restrict__ Wqkv, const float* __restrict__ Wout,
    __hip_bfloat16* __restrict__ WqkvT, __hip_bfloat16* __restrict__ WoutT) {
  const int z = blockIdx.z;
  if (z == 1 && blockIdx.x >= 32) return;
  const float* in = z ? Wout : Wqkv;
  __hip_bfloat16* out = z ? WoutT : WqkvT;
  const int R = 1024, C = z ? 1024 : 3072;
  __shared__ __hip_bfloat16 tile[32][33];
  const int c0 = blockIdx.x * 32, r0 = blockIdx.y * 32;
  const int tx = threadIdx.x & 31, ty = threadIdx.x >> 5;  // ty 0..7
  #pragma unroll
  for (int i = ty; i < 32; i += 8)
    tile[i][tx] = __float2bfloat16(in[(size_t)(r0 + i) * C + (c0 + tx)]);
  __syncthreads();
  #pragma unroll
  for (int i = ty; i < 32; i += 8)
    out[(size_t)(c0 + i) * R + (r0 + tx)] = tile[tx][i];
}

// ---------------------------------------------------------------------------
// gemm_bt: C (MxN, OutT) = A (MxK, row-major bf16) @ Bt^T  (Bt is NxK bf16)
// 128xBN tile (BN = 128 or 64), BK=64, 256 threads = 4 waves.
// m97-style global_load_lds width=16 staging, stride-64 LDS + XOR chunk
// swizzle (r6-verified). BN=64 for gemm2 (r11: grid 256->512). Frozen.
// ---------------------------------------------------------------------------
template <typename OutT, int BN>
__global__ __launch_bounds__(256) void gemm_bt(
    const __hip_bfloat16* __restrict__ A,
    const __hip_bfloat16* __restrict__ Bt,
    OutT* __restrict__ C,
    int M, int N, int K) {
  __shared__ __hip_bfloat16 lA[128][64];
  __shared__ __hip_bfloat16 lB[BN][64];
  constexpr int NJ = BN / 32;                    // j-tiles of 16 per wave
  const int t = threadIdx.x;
  const int lane = t & 63, wave = t >> 6;
  const int quad = lane >> 4, ln = lane & 15;
  const int m0 = blockIdx.y * 128, n0 = blockIdx.x * BN;
  const int wm = (wave >> 1) * 64, wn = (wave & 1) * (BN / 2);
  const int srow = lane >> 3;                    // 0..7
  const int schunk = ((lane & 7) ^ srow) * 8;    // swizzled elem offset

  float4v acc[4][NJ];
  #pragma unroll
  for (int i = 0; i < 4; ++i)
    #pragma unroll
    for (int j = 0; j < NJ; ++j)
      acc[i][j] = (float4v){0.f, 0.f, 0.f, 0.f};

  for (int kt = 0; kt < K; kt += 64) {
    __syncthreads();   // previous iter's frag reads done before DMA overwrite
    #pragma unroll
    for (int q = 0; q < 4; ++q) {
      const int rbase = wave * 32 + q * 8;       // A: 128 rows, 4 groups/wave
      __builtin_amdgcn_global_load_lds(
          (const __attribute__((address_space(1))) void*)
              (A + (size_t)(m0 + rbase + srow) * K + kt + schunk),
          (__attribute__((address_space(3))) void*)&lA[rbase][0], 16, 0, 0);
    }
    #pragma unroll
    for (int g = 0; g < BN / 32; ++g) {
      const int rbase = wave * (BN / 4) + g * 8; // B: BN rows, BN/32 groups/wave
      __builtin_amdgcn_global_load_lds(
          (const __attribute__((address_space(1))) void*)
              (Bt + (size_t)(n0 + rbase + srow) * K + kt + schunk),
          (__attribute__((address_space(3))) void*)&lB[rbase][0], 16, 0, 0);
    }
    __syncthreads();   // vmcnt(0) drain: DMA complete, LDS visible
    #pragma unroll
    for (int step = 0; step < 2; ++step) {
      short8 af[4], bf[NJ];
      #pragma unroll
      for (int i = 0; i < 4; ++i)
        af[i] = *(const short8*)&lA[wm + i * 16 + ln][((step * 4 + quad) ^ (ln & 7)) * 8];
      #pragma unroll
      for (int j = 0; j < NJ; ++j)
        bf[j] = *(const short8*)&lB[wn + j * 16 + ln][((step * 4 + quad) ^ (ln & 7)) * 8];
      #pragma unroll
      for (int i = 0; i < 4; ++i)
        #pragma unroll
        for (int j = 0; j < NJ; ++j)
          acc[i][j] = __builtin_amdgcn_mfma_f32_16x16x32_bf16(af[i], bf[j], acc[i][j], 0, 0, 0);
    }
  }
  // Epilogue. C/D layout: row = quad*4 + reg, col = lane&15 (m89/m91-verified).
  #pragma unroll
  for (int i = 0; i < 4; ++i)
    #pragma unroll
    for (int j = 0; j < NJ; ++j)
      #pragma unroll
      for (int r = 0; r < 4; ++r) {
        const int row = m0 + wm + i * 16 + quad * 4 + r;
        const int col = n0 + wn + j * 16 + ln;
        if constexpr (__is_same(OutT, float))
          C[(size_t)row * N + col] = acc[i][j][r];
        else
          C[(size_t)row * N + col] = __float2bfloat16(acc[i][j][r]);
      }
}

// ---------------------------------------------------------------------------
// Fused QKV prep (table-driven): rope(Q,K) reshape + V transpose, one qkv
// pass, zero transcendentals (reads rope_table from L2).
// Q scaled by (1/8)*log2(e): attention scores live in the exp2 domain.
// ---------------------------------------------------------------------------
__global__ __launch_bounds__(256) void qkv_prep(
    const __hip_bfloat16* __restrict__ qkv,
    const float2* __restrict__ tab,
    __hip_bfloat16* __restrict__ Q,
    __hip_bfloat16* __restrict__ K,
    __hip_bfloat16* __restrict__ Vt) {
  __shared__ __hip_bfloat16 tile[64][65];
  const int s0 = blockIdx.x * 64;
  const int bh = blockIdx.y;
  const int h = bh & 15, b = bh >> 4;
  const int t = threadIdx.x;

  // --- RoPE for Q,K: t = (s_local 0..7) x (pair 0..31), 8 passes over s ---
  const int pr = t & 31, sl = t >> 5;
  const int d0 = pr * 2;
  const float qs = 0.125f * 1.44269504088896340736f;  // (1/8)*log2(e)
  #pragma unroll
  for (int ss = sl; ss < 64; ss += 8) {
    const int s = s0 + ss;
    const float2 cssn = tab[(size_t)s * 32 + pr];
    const float cs = cssn.x, sn = cssn.y;
    const size_t in_base = (size_t)(b * 2048 + s) * 3072;
    const size_t o = ((size_t)bh * 2048 + s) * 64 + d0;

    __hip_bfloat162 q2 = *(const __hip_bfloat162*)&qkv[in_base + h * 64 + d0];
    float x1 = __bfloat162float(q2.x), x2 = __bfloat162float(q2.y);
    __hip_bfloat162 qo;
    qo.x = __float2bfloat16((x1 * cs - x2 * sn) * qs);
    qo.y = __float2bfloat16((x1 * sn + x2 * cs) * qs);
    *(__hip_bfloat162*)&Q[o] = qo;

    __hip_bfloat162 k2 = *(const __hip_bfloat162*)&qkv[in_base + 1024 + h * 64 + d0];
    x1 = __bfloat162float(k2.x); x2 = __bfloat162float(k2.y);
    __hip_bfloat162 ko;
    ko.x = __float2bfloat16(x1 * cs - x2 * sn);
    ko.y = __float2bfloat16(x1 * sn + x2 * cs);
    *(__hip_bfloat162*)&K[o] = ko;
  }

  // --- V transpose: (s,d) -> Vt[bh][d][s] ---
  const int tx = t & 63, ty = t >> 6;  // ty 0..3
  #pragma unroll
  for (int i = ty; i < 64; i += 4)
    tile[i][tx] = qkv[(size_t)(b * 2048 + s0 + i) * 3072 + 2048 + h * 64 + tx];
  __syncthreads();
  #pragma unroll
  for (int i = ty; i < 64; i += 4)
    Vt[((size_t)bh * 64 + i) * 2048 + s0 + tx] = tile[tx][i];
}

// ---------------------------------------------------------------------------
// Flash-style causal attention — FROZEN at the r7/r11 form (~45-47 µs).
// Four theories tested and falsified (DS-count r9, LDS-BW r10, TLP r11);
// the floor is the per-iteration VALU chain (16 quarter-rate v_exp_f32 +
// cvt + staging per wave-iter) — invariant across decompositions.
// 1024 single-qt blocks, longest-first; dbuf global_load_lds; 1 barrier/iter.
// ---------------------------------------------------------------------------
__global__ __launch_bounds__(256) void attention(
    const __hip_bfloat16* __restrict__ Q,
    const __hip_bfloat16* __restrict__ K,
    const __hip_bfloat16* __restrict__ Vt,
    __hip_bfloat16* __restrict__ attn) {
  __shared__ __hip_bfloat16 lK[2][64][64];    // [buf][sk][d]   XOR-swizzled
  __shared__ __hip_bfloat16 lV[2][64][64];    // [buf][d][sk]   XOR-swizzled
  __shared__ __hip_bfloat16 lP[4][16][72];    // per-wave [q][sk]
  const int t = threadIdx.x;
  const int lane = t & 63, w = t >> 6;
  const int quad = lane >> 4, ln = lane & 15;
  const int id = blockIdx.x;
  const int bh = id & 31;                     // fast index -> XCD spread
  const int qt = 31 - (id >> 5);              // longest q-tiles first
  const int q0 = qt * 64;
  const size_t base = (size_t)bh * 2048 * 64;
  const __hip_bfloat16* Qb = Q + base;
  const __hip_bfloat16* Kb = K + base;
  const __hip_bfloat16* Vb = Vt + base;
  const int b = bh >> 4, h = bh & 15;

  short8 ones;
  #pragma unroll
  for (int i = 0; i < 8; ++i) ones[i] = (short)0x3F80;   // bf16 1.0

  const int srow = lane >> 3;                    // 0..7
  const int schunk = ((lane & 7) ^ srow) * 8;    // swizzled elem offset
  const int rb0 = w * 16;                        // this wave's staging rows

  // stage kt=0 into buf 0 (each wave: 2 K-row-groups + 2 V-row-groups)
  #pragma unroll
  for (int g = 0; g < 2; ++g) {
    const int rbase = rb0 + g * 8;
    __builtin_amdgcn_global_load_lds(
        (const __attribute__((address_space(1))) void*)
            (Kb + (size_t)(rbase + srow) * 64 + schunk),
        (__attribute__((address_space(3))) void*)&lK[0][rbase][0], 16, 0, 0);
    __builtin_amdgcn_global_load_lds(
        (const __attribute__((address_space(1))) void*)
            (Vb + (size_t)(rbase + srow) * 2048 + schunk),
        (__attribute__((address_space(3))) void*)&lV[0][rbase][0], 16, 0, 0);
  }

  // Q fragment (A-operand): m = ln, k = step*32 + quad*8 + j
  short8 qf[2];
  {
    const size_t qrow = (size_t)(q0 + w * 16 + ln) * 64;
    qf[0] = *(const short8*)(Qb + qrow + quad * 8);
    qf[1] = *(const short8*)(Qb + qrow + 32 + quad * 8);
  }

  float4v acc_o[4];
  #pragma unroll
  for (int dt = 0; dt < 4; ++dt) acc_o[dt] = (float4v){0.f, 0.f, 0.f, 0.f};
  float4v acc_l = (float4v){0.f, 0.f, 0.f, 0.f};

  for (int kt = 0; kt <= qt; ++kt) {
    const int buf = kt & 1;
    __syncthreads();   // drains DMA(kt); frees buf^1

    if (kt < qt) {     // prefetch kt+1 into the other buffer — after barrier
      #pragma unroll
      for (int g = 0; g < 2; ++g) {
        const int rbase = rb0 + g * 8;
        __builtin_amdgcn_global_load_lds(
            (const __attribute__((address_space(1))) void*)
                (Kb + (size_t)((kt + 1) * 64 + rbase + srow) * 64 + schunk),
            (__attribute__((address_space(3))) void*)&lK[buf ^ 1][rbase][0], 16, 0, 0);
        __builtin_amdgcn_global_load_lds(
            (const __attribute__((address_space(1))) void*)
                (Vb + (size_t)(rbase + srow) * 2048 + (kt + 1) * 64 + schunk),
            (__attribute__((address_space(3))) void*)&lV[buf ^ 1][rbase][0], 16, 0, 0);
      }
    }

    // S = Q K^T (exp2 domain; Q pre-scaled); B-operand n = sk = ln
    float4v s4[4];
    #pragma unroll
    for (int nt = 0; nt < 4; ++nt) {
      float4v a = (float4v){0.f, 0.f, 0.f, 0.f};
      #pragma unroll
      for (int step = 0; step < 2; ++step) {
        short8 kf = *(const short8*)&lK[buf][nt * 16 + ln][((step * 4 + quad) ^ (ln & 7)) * 8];
        a = __builtin_amdgcn_mfma_f32_16x16x32_bf16(qf[step], kf, a, 0, 0, 0);
      }
      s4[nt] = a;
    }
    if (kt == qt) {  // diagonal tile: causal mask (exp2(-64) ~ 5e-20 -> 0)
      #pragma unroll
      for (int nt = 0; nt < 4; ++nt)
        #pragma unroll
        for (int r = 0; r < 4; ++r) {
          const int sk = kt * 64 + nt * 16 + ln;
          const int qr = q0 + w * 16 + quad * 4 + r;
          if (sk > qr) s4[nt][r] = -64.f;
        }
    }
    // P = exp2(S), straight to LDS in C-layout (wave-private, no barrier)
    #pragma unroll
    for (int nt = 0; nt < 4; ++nt)
      #pragma unroll
      for (int r = 0; r < 4; ++r)
        lP[w][quad * 4 + r][nt * 16 + ln] = __float2bfloat16(exp2f(s4[nt][r]));
    // O += P V ; l += P 1
    #pragma unroll
    for (int step = 0; step < 2; ++step) {
      short8 pf = *(const short8*)&lP[w][ln][step * 32 + quad * 8];
      acc_l = __builtin_amdgcn_mfma_f32_16x16x32_bf16(pf, ones, acc_l, 0, 0, 0);
      #pragma unroll
      for (int dt = 0; dt < 4; ++dt) {
        short8 vf = *(const short8*)&lV[buf][dt * 16 + ln][((step * 4 + quad) ^ (ln & 7)) * 8];
        acc_o[dt] = __builtin_amdgcn_mfma_f32_16x16x32_bf16(pf, vf, acc_o[dt], 0, 0, 0);
      }
    }
  }

  // write O / l  to attn in (b, s, h*64+d) layout
  float inv_l[4];
  #pragma unroll
  for (int r = 0; r < 4; ++r) inv_l[r] = 1.0f / acc_l[r];
  #pragma unroll
  for (int dt = 0; dt < 4; ++dt)
    #pragma unroll
    for (int r = 0; r < 4; ++r) {
      const int qr = q0 + w * 16 + quad * 4 + r;
      const size_t rg = (size_t)(b * 2048 + qr);
      const int col = h * 64 + dt * 16 + ln;
      attn[rg * 1024 + col] = __float2bfloat16(acc_o[dt][r] * inv_l[r]);
    }
}

// ---------------------------------------------------------------------------
extern "C" void kernel_launch(void* const* d_in, const int* in_sizes, int n_in,
                              void* d_out, int out_size, void* d_ws, size_t ws_size,
                              hipStream_t stream) {
  const float* x    = (const float*)d_in[0];  // (2,2048,1024) fp32
  const float* Wqkv = (const float*)d_in[1];  // (1024,3072)   fp32
  const float* Wout = (const float*)d_in[2];  // (1024,1024)   fp32
  float* out = (float*)d_out;                 // (2,2048,1024) fp32

  __hip_bfloat16* ws = (__hip_bfloat16*)d_ws;
  __hip_bfloat16* xb    = ws;                          // 4096*1024
  __hip_bfloat16* WqkvT = xb    + (size_t)4096 * 1024; // 3072*1024
  __hip_bfloat16* WoutT = WqkvT + (size_t)3072 * 1024; // 1024*1024
  __hip_bfloat16* qkv   = WoutT + (size_t)1024 * 1024; // 4096*3072
  __hip_bfloat16* Q     = qkv   + (size_t)4096 * 3072; // 32*2048*64
  __hip_bfloat16* K     = Q     + (size_t)32 * 2048 * 64;
  __hip_bfloat16* Vt    = K     + (size_t)32 * 2048 * 64;
  __hip_bfloat16* attn  = Vt    + (size_t)32 * 2048 * 64;  // dedicated
  float2*         tab   = (float2*)(attn + (size_t)4096 * 1024);  // 2048x32

  cvt_f32_bf16<<<4096, 256, 0, stream>>>(x, xb, 4096 * 1024 / 4);
  rope_table<<<256, 256, 0, stream>>>(tab);
  prep_weights<<<dim3(96, 32, 2), 256, 0, stream>>>(Wqkv, Wout, WqkvT, WoutT);
  gemm_bt<__hip_bfloat16, 128><<<dim3(3072 / 128, 4096 / 128), 256, 0, stream>>>(xb, WqkvT, qkv, 4096, 3072, 1024);
  qkv_prep<<<dim3(32, 32), 256, 0, stream>>>(qkv, tab, Q, K, Vt);
  attention<<<1024, 256, 0, stream>>>(Q, K, Vt, attn);
  gemm_bt<float, 64><<<dim3(1024 / 64, 4096 / 128), 256, 0, stream>>>(attn, WoutT, out, 4096, 1024, 1024);
}